// Round 1
// baseline (3333.857 us; speedup 1.0000x reference)
//
#include <hip/hip_runtime.h>
#include <math.h>

#define TOK  1024
#define HSZ  1024
#define DIM  128
#define NWRDC 32000
#define NTGTC 2000

// ---------------------------------------------------------------------------
// pcpy[t] = sum_k ( (sum_h ctx[t][h] * W_cpy[h][k]) + b_cpy[k] ) * ctx[t][k]
// 8 tokens per block, 256 threads.
// ---------------------------------------------------------------------------
__global__ __launch_bounds__(256) void pcpy_kernel(
    const float* __restrict__ ctx, const float* __restrict__ Wc,
    const float* __restrict__ bc, float* __restrict__ out_pcpy)
{
    __shared__ float cx[8][HSZ];
    __shared__ float red[8][4];
    const int tid = (int)threadIdx.x;
    const int t0  = (int)blockIdx.x * 8;
    {
        const int tt   = tid >> 5;
        const int base = (tid & 31) * 32;
        const float* src = ctx + (size_t)(t0 + tt) * HSZ + base;
        #pragma unroll
        for (int k = 0; k < 32; k += 4)
            *(float4*)&cx[tt][base + k] = *(const float4*)(src + k);
    }
    __syncthreads();

    float y[8][4];
    #pragma unroll
    for (int i = 0; i < 8; ++i)
        #pragma unroll
        for (int j = 0; j < 4; ++j) y[i][j] = 0.f;

    for (int h = 0; h < HSZ; ++h) {
        float c8[8];
        #pragma unroll
        for (int i = 0; i < 8; ++i) c8[i] = cx[i][h];
        const float* wr = Wc + (size_t)h * HSZ + tid;
        #pragma unroll
        for (int j = 0; j < 4; ++j) {
            float w = wr[256 * j];
            #pragma unroll
            for (int i = 0; i < 8; ++i) y[i][j] = fmaf(w, c8[i], y[i][j]);
        }
    }

    float part[8];
    #pragma unroll
    for (int i = 0; i < 8; ++i) part[i] = 0.f;
    #pragma unroll
    for (int j = 0; j < 4; ++j) {
        const int k = tid + 256 * j;
        const float bk = bc[k];
        #pragma unroll
        for (int i = 0; i < 8; ++i) part[i] += (y[i][j] + bk) * cx[i][k];
    }

    const int lane = tid & 63, wid = tid >> 6;
    #pragma unroll
    for (int i = 0; i < 8; ++i) {
        float v = part[i];
        for (int off = 32; off > 0; off >>= 1) v += __shfl_down(v, off, 64);
        if (lane == 0) red[i][wid] = v;
    }
    __syncthreads();
    if (tid < 8)
        out_pcpy[t0 + tid] = red[tid][0] + red[tid][1] + red[tid][2] + red[tid][3];
}

// ---------------------------------------------------------------------------
// Fused head kernel: for a 64-token tile and a chunk of vocab tiles,
// compute logits = ctx@W + b + g, e = exp(s), accumulate:
//   Zpart[t]   = sum e
//   best[t]    = (max s, argmax col)
//   Epart[t,d] = sum e * emb[col][d]
// Partials written to workspace, combined later. No atomics, deterministic.
// block: 256 threads = 16(ty) x 16(tx); thread tile 4 tokens x 4 cols (main),
// 4 tokens x 8 dims (emb GEMM).
// ---------------------------------------------------------------------------
__global__ __launch_bounds__(256) void head_kernel(
    const float* __restrict__ ctx,  // [TOK][HSZ]
    const float* __restrict__ W,    // [HSZ][V]
    const float* __restrict__ bias, // [V]
    const float* __restrict__ g,    // [TOK][ldg]
    const float* __restrict__ emb,  // [V][DIM]
    int V, int ldg, int tiles_per_split, int n_tiles,
    float* __restrict__ wsW, float* __restrict__ wsBV,
    int* __restrict__ wsBI, float* __restrict__ wsE)
{
    __shared__ float As[16][68];   // ctx chunk, transposed [hh][token]
    __shared__ float Bs[16][68];   // W chunk [hh][col]
    __shared__ float Ps[64][68];   // exp tile [token][col]
    __shared__ float Es[64][132];  // emb tile [col][d]

    const int tid = (int)threadIdx.x;
    const int tx  = tid & 15;
    const int ty  = tid >> 4;
    const int t0  = (int)blockIdx.x * 64;
    const int split = (int)blockIdx.y;
    int tile_beg = split * tiles_per_split;
    int tile_end = tile_beg + tiles_per_split;
    if (tile_end > n_tiles) tile_end = n_tiles;

    float Eacc[4][8];
    #pragma unroll
    for (int i = 0; i < 4; ++i)
        #pragma unroll
        for (int j = 0; j < 8; ++j) Eacc[i][j] = 0.f;
    float wsum[4] = {0.f, 0.f, 0.f, 0.f};
    float bval[4] = {-INFINITY, -INFINITY, -INFINITY, -INFINITY};
    int   bidx[4] = {0, 0, 0, 0};

    const int rA  = tid >> 2;          // 0..63 token row for A staging
    const int hqA = (tid & 3) << 2;    // 0,4,8,12
    const int hhB = tid >> 4;          // 0..15 h row for B staging
    const int cqB = (tid & 15) << 2;   // 0..60

    for (int tt = tile_beg; tt < tile_end; ++tt) {
        const int c0 = tt * 64;
        float acc[4][4];
        #pragma unroll
        for (int i = 0; i < 4; ++i)
            #pragma unroll
            for (int j = 0; j < 4; ++j) acc[i][j] = 0.f;

        for (int h0 = 0; h0 < HSZ; h0 += 16) {
            // load into regs first (no LDS), then barrier, then write LDS
            float4 va = *(const float4*)&ctx[(size_t)(t0 + rA) * HSZ + h0 + hqA];
            const int colB = c0 + cqB;
            const float* wrow = W + (size_t)(h0 + hhB) * V;
            float4 vb;
            if (colB + 3 < V) {
                vb = *(const float4*)(wrow + colB);
            } else {
                vb.x = (colB + 0 < V) ? wrow[colB + 0] : 0.f;
                vb.y = (colB + 1 < V) ? wrow[colB + 1] : 0.f;
                vb.z = (colB + 2 < V) ? wrow[colB + 2] : 0.f;
                vb.w = (colB + 3 < V) ? wrow[colB + 3] : 0.f;
            }
            __syncthreads();
            As[hqA + 0][rA] = va.x; As[hqA + 1][rA] = va.y;
            As[hqA + 2][rA] = va.z; As[hqA + 3][rA] = va.w;
            *(float4*)&Bs[hhB][cqB] = vb;
            __syncthreads();
            #pragma unroll
            for (int hh = 0; hh < 16; ++hh) {
                float4 a4 = *(const float4*)&As[hh][ty << 2];
                float4 b4 = *(const float4*)&Bs[hh][tx << 2];
                float aarr[4] = {a4.x, a4.y, a4.z, a4.w};
                float barr[4] = {b4.x, b4.y, b4.z, b4.w};
                #pragma unroll
                for (int i = 0; i < 4; ++i)
                    #pragma unroll
                    for (int j = 0; j < 4; ++j)
                        acc[i][j] = fmaf(aarr[i], barr[j], acc[i][j]);
            }
        }

        // ---- epilogue: stage emb tile, exp+stats, then E-GEMM ----
        {
            const int c  = tid >> 2;
            const int dq = (tid & 3) << 5;
            const int col = c0 + c;
            if (col < V) {
                const float* er = emb + (size_t)col * DIM + dq;
                #pragma unroll
                for (int k = 0; k < 32; k += 4)
                    *(float4*)&Es[c][dq + k] = *(const float4*)(er + k);
            } else {
                float4 z = {0.f, 0.f, 0.f, 0.f};
                #pragma unroll
                for (int k = 0; k < 32; k += 4)
                    *(float4*)&Es[c][dq + k] = z;
            }
        }
        #pragma unroll
        for (int i = 0; i < 4; ++i) {
            const int token = t0 + (ty << 2) + i;
            float pv[4];
            #pragma unroll
            for (int j = 0; j < 4; ++j) {
                const int col = c0 + (tx << 2) + j;
                float e = 0.f;
                if (col < V) {
                    float s = acc[i][j] + bias[col] + g[(size_t)token * ldg + col];
                    e = __expf(s);
                    wsum[i] += e;
                    if (s > bval[i]) { bval[i] = s; bidx[i] = col; }
                }
                pv[j] = e;
            }
            float4 p4 = {pv[0], pv[1], pv[2], pv[3]};
            *(float4*)&Ps[(ty << 2) + i][tx << 2] = p4;
        }
        __syncthreads();
        #pragma unroll 4
        for (int c = 0; c < 64; ++c) {
            float ap[4];
            #pragma unroll
            for (int i = 0; i < 4; ++i) ap[i] = Ps[(ty << 2) + i][c];
            float4 e0 = *(const float4*)&Es[c][tx << 3];
            float4 e1 = *(const float4*)&Es[c][(tx << 3) + 4];
            float be[8] = {e0.x, e0.y, e0.z, e0.w, e1.x, e1.y, e1.z, e1.w};
            #pragma unroll
            for (int i = 0; i < 4; ++i)
                #pragma unroll
                for (int j = 0; j < 8; ++j)
                    Eacc[i][j] = fmaf(ap[i], be[j], Eacc[i][j]);
        }
        __syncthreads();
    }

    // ---- write E partials (unique owner per (token, d)) ----
    #pragma unroll
    for (int i = 0; i < 4; ++i) {
        const int r = (ty << 2) + i;
        const size_t o = ((size_t)split * TOK + t0 + r) * DIM + (tx << 3);
        float4 v0 = {Eacc[i][0], Eacc[i][1], Eacc[i][2], Eacc[i][3]};
        float4 v1 = {Eacc[i][4], Eacc[i][5], Eacc[i][6], Eacc[i][7]};
        *(float4*)&wsE[o]     = v0;
        *(float4*)&wsE[o + 4] = v1;
    }

    // ---- reduce Z and best across the 16 tx columns (reuse LDS) ----
    __syncthreads();
    float* RV = &As[0][0];        // 16*68 = 1088 >= 64*17
    int*   RI = (int*)&Bs[0][0];
    #pragma unroll
    for (int i = 0; i < 4; ++i) {
        const int r = (ty << 2) + i;
        Ps[r][tx]       = wsum[i];
        RV[r * 17 + tx] = bval[i];
        RI[r * 17 + tx] = bidx[i];
    }
    __syncthreads();
    if (tid < 64) {
        float s = 0.f, bv = -INFINITY; int bi = 0;
        #pragma unroll
        for (int x = 0; x < 16; ++x) {
            s += Ps[tid][x];
            float vv = RV[tid * 17 + x];
            int   ii = RI[tid * 17 + x];
            if (vv > bv || (vv == bv && ii < bi)) { bv = vv; bi = ii; }
        }
        const size_t o = (size_t)split * TOK + t0 + tid;
        wsW[o]  = s;
        wsBV[o] = bv;
        wsBI[o] = bi;
    }
}

// ---------------------------------------------------------------------------
// Combine: merge partials, add copy column, pick words, select outputs.
// 1 block per token, 128 threads (one per output dim).
// ---------------------------------------------------------------------------
__global__ __launch_bounds__(128) void combine_kernel(
    const int* __restrict__ inp_word, const float* __restrict__ masks,
    const int* __restrict__ spt_mask, const int* __restrict__ tgt_ids,
    const float* __restrict__ word_emb, const float* __restrict__ pcpy,
    const float* __restrict__ g_nrm,
    const float* __restrict__ nW, const float* __restrict__ nBV,
    const int* __restrict__ nBI, const float* __restrict__ nE, int NVn,
    const float* __restrict__ sW, const float* __restrict__ sBV,
    const int* __restrict__ sBI, const float* __restrict__ sE, int NVs,
    float* __restrict__ out)
{
    const int t = (int)blockIdx.x;
    const int d = (int)threadIdx.x;

    // normal head merge
    float Wn = 0.f, En = 0.f, bv = -INFINITY; int bi = 0;
    for (int v = 0; v < NVn; ++v) {
        const size_t o = (size_t)v * TOK + t;
        Wn += nW[o];
        En += nE[o * DIM + d];
        float vv = nBV[o]; int ii = nBI[o];
        if (vv > bv || (vv == bv && ii < bi)) { bv = vv; bi = ii; }
    }
    const int iw = inp_word[t];
    const float sc = pcpy[t] + g_nrm[(size_t)t * (NWRDC + 1) + NWRDC];
    const float ec = __expf(sc);
    Wn += ec;
    En += ec * word_emb[(size_t)iw * DIM + d];
    const int ynrm = (sc > bv) ? iw : bi;   // tie -> vocab index (first max)

    // special head merge
    float Ws = 0.f, Ese = 0.f, sv = -INFINITY; int si = 0;
    for (int v = 0; v < NVs; ++v) {
        const size_t o = (size_t)v * TOK + t;
        Ws += sW[o];
        Ese += sE[o * DIM + d];
        float vv = sBV[o]; int ii = sBI[o];
        if (vv > sv || (vv == sv && ii < si)) { sv = vv; si = ii; }
    }
    const int yspt = tgt_ids[si];

    const float sptf = (float)spt_mask[t];
    const float nrmf = (1.f - sptf) * masks[t];

    float eo; int obf;
    if (sptf > 0.f)      { eo = Ese / Ws; obf = yspt; }
    else if (nrmf > 0.f) { eo = En / Wn;  obf = ynrm; }
    else                 { obf = iw; eo = word_emb[(size_t)iw * DIM + d]; }

    out[(size_t)t * DIM + d] = eo;
    if (d == 0) {
        out[(size_t)TOK * DIM + t]       = (float)obf;
        out[(size_t)TOK * DIM + TOK + t] = sptf;
    }
}

// ---------------------------------------------------------------------------
extern "C" void kernel_launch(void* const* d_in, const int* in_sizes, int n_in,
                              void* d_out, int out_size, void* d_ws, size_t ws_size,
                              hipStream_t stream)
{
    const int*   inp_word = (const int*)d_in[0];
    const float* masks    = (const float*)d_in[1];
    const int*   spt_mask = (const int*)d_in[2];
    const int*   tgt_ids  = (const int*)d_in[3];
    const float* ctx      = (const float*)d_in[4];
    const float* W_spt    = (const float*)d_in[5];
    const float* b_spt    = (const float*)d_in[6];
    const float* W_nrm    = (const float*)d_in[7];
    const float* b_nrm    = (const float*)d_in[8];
    const float* W_cpy    = (const float*)d_in[9];
    const float* b_cpy    = (const float*)d_in[10];
    const float* word_emb = (const float*)d_in[11];
    const float* word_emb_tgt = (const float*)d_in[12];
    const float* g_spt    = (const float*)d_in[13];
    const float* g_nrm    = (const float*)d_in[14];
    float* out = (float*)d_out;

    // workspace carve: split counts adapt to ws_size (deterministic)
    const size_t ws_f = ws_size / 4;
    const size_t per_split = (size_t)TOK * (DIM + 3);   // Z + bestv + besti + E
    size_t avail = (ws_f > 1024) ? (ws_f - 1024) / per_split : 2;
    if (avail < 2) avail = 2;
    int NVs = (int)(avail / 5); if (NVs < 1) NVs = 1; if (NVs > 4)  NVs = 4;
    long nv = (long)avail - NVs;
    int NVn = (nv < 1) ? 1 : (nv > 16 ? 16 : (int)nv);

    float* pcpy = (float*)d_ws;                         // [1024]
    float* nWp  = pcpy + 1024;
    float* nBVp = nWp  + (size_t)NVn * TOK;
    int*   nBIp = (int*)(nBVp + (size_t)NVn * TOK);
    float* nEp  = (float*)(nBIp + (size_t)NVn * TOK);
    float* sWp  = nEp  + (size_t)NVn * TOK * DIM;
    float* sBVp = sWp  + (size_t)NVs * TOK;
    int*   sBIp = (int*)(sBVp + (size_t)NVs * TOK);
    float* sEp  = (float*)(sBIp + (size_t)NVs * TOK);

    const int ntile_n = NWRDC / 64;                     // 500
    const int tps_n   = (ntile_n + NVn - 1) / NVn;
    const int ntile_s = (NTGTC + 63) / 64;              // 32
    const int tps_s   = (ntile_s + NVs - 1) / NVs;

    hipLaunchKernelGGL(pcpy_kernel, dim3(TOK / 8), dim3(256), 0, stream,
                       ctx, W_cpy, b_cpy, pcpy);
    hipLaunchKernelGGL(head_kernel, dim3(TOK / 64, NVn), dim3(256), 0, stream,
                       ctx, W_nrm, b_nrm, g_nrm, word_emb, NWRDC, NWRDC + 1,
                       tps_n, ntile_n, nWp, nBVp, nBIp, nEp);
    hipLaunchKernelGGL(head_kernel, dim3(TOK / 64, NVs), dim3(256), 0, stream,
                       ctx, W_spt, b_spt, g_spt, word_emb_tgt, NTGTC, NTGTC,
                       tps_s, ntile_s, sWp, sBVp, sBIp, sEp);
    hipLaunchKernelGGL(combine_kernel, dim3(TOK), dim3(DIM), 0, stream,
                       inp_word, masks, spt_mask, tgt_ids, word_emb, pcpy, g_nrm,
                       nWp, nBVp, nBIp, nEp, NVn,
                       sWp, sBVp, sBIp, sEp, NVs, out);
    (void)in_sizes; (void)n_in; (void)out_size;
}

// Round 2
// 897.693 us; speedup vs baseline: 3.7138x; 3.7138x over previous
//
#include <hip/hip_runtime.h>
#include <math.h>

#define TOK   1024
#define HSZ   1024
#define DIM   128
#define NWRDC 32000
#define NTGTC 2000

typedef __attribute__((ext_vector_type(8))) short bf16x8;
typedef __attribute__((ext_vector_type(4))) float f32x4;

__device__ __forceinline__ ushort f2bf(float x) {
    union { float f; uint u; } c; c.f = x;
    return (ushort)((c.u + 0x7fffu + ((c.u >> 16) & 1u)) >> 16);
}
__device__ __forceinline__ float bf2f(ushort h) {
    union { uint u; float f; } c; c.u = ((uint)h) << 16;
    return c.f;
}
__device__ __forceinline__ uint4 pk8(const ushort v[8]) {
    uint4 u;
    u.x = (uint)v[0] | ((uint)v[1] << 16);
    u.y = (uint)v[2] | ((uint)v[3] << 16);
    u.z = (uint)v[4] | ((uint)v[5] << 16);
    u.w = (uint)v[6] | ((uint)v[7] << 16);
    return u;
}

// ---------------------------------------------------------------------------
// split ctx into 3 bf16 terms: x ~= hi + mid + lo (hi+mid used as the 2-term
// split by head_mfma; all 3 used by gemm_cpy for f32-class precision)
// ---------------------------------------------------------------------------
__global__ __launch_bounds__(256) void split_ctx3(
    const float* __restrict__ x, ushort* __restrict__ hp,
    ushort* __restrict__ mp, ushort* __restrict__ lp)
{
    const int i4 = (blockIdx.x * 256 + threadIdx.x) * 4;
    float4 v = *(const float4*)(x + i4);
    float xs[4] = {v.x, v.y, v.z, v.w};
    ushort hh[4], mm[4], ll[4];
    #pragma unroll
    for (int k = 0; k < 4; ++k) {
        ushort h = f2bf(xs[k]);
        float r1 = xs[k] - bf2f(h);
        ushort m = f2bf(r1);
        ushort l = f2bf(r1 - bf2f(m));
        hh[k] = h; mm[k] = m; ll[k] = l;
    }
    uint2 u;
    u.x = (uint)hh[0] | ((uint)hh[1] << 16); u.y = (uint)hh[2] | ((uint)hh[3] << 16);
    *(uint2*)(hp + i4) = u;
    u.x = (uint)mm[0] | ((uint)mm[1] << 16); u.y = (uint)mm[2] | ((uint)mm[3] << 16);
    *(uint2*)(mp + i4) = u;
    u.x = (uint)ll[0] | ((uint)ll[1] << 16); u.y = (uint)ll[2] | ((uint)ll[3] << 16);
    *(uint2*)(lp + i4) = u;
}

// ---------------------------------------------------------------------------
// gemm_cpy: C = ctx @ W_cpy  (1024x1024x1024), 3-term split bf16 MFMA,
// 6 passes -> ~2^-25 relative error (argmax-safe). 128x128 tile, 4 waves.
// ---------------------------------------------------------------------------
__global__ __launch_bounds__(256, 2) void gemm_cpy(
    const ushort* __restrict__ ahi, const ushort* __restrict__ amd,
    const ushort* __restrict__ alo, const float* __restrict__ W,
    float* __restrict__ C)
{
    __shared__ __align__(16) ushort sm[30720];  // 6 x 128x40
    ushort* Ah = sm;
    ushort* Am = sm + 5120;
    ushort* Al = sm + 10240;
    ushort* Bh = sm + 15360;
    ushort* Bm = sm + 20480;
    ushort* Bl = sm + 25600;

    const int tid  = threadIdx.x;
    const int lane = tid & 63;
    const int fr   = lane & 15;
    const int fg   = lane >> 4;
    const int w    = tid >> 6;
    const int wrow = w >> 1;
    const int wcol = w & 1;
    const int t0   = blockIdx.x * 128;
    const int c0   = blockIdx.y * 128;

    const int arow = tid >> 2, akc = tid & 3;
    const int bcol = tid & 127, bkc0 = tid >> 7;

    f32x4 zero4 = {0.f, 0.f, 0.f, 0.f};
    f32x4 acc[4][4];
    #pragma unroll
    for (int i = 0; i < 4; ++i)
        #pragma unroll
        for (int j = 0; j < 4; ++j) acc[i][j] = zero4;

    for (int h0 = 0; h0 < HSZ; h0 += 32) {
        uint4 aH[2], aM[2], aL[2];
        float bx[2][8];
        #pragma unroll
        for (int rr = 0; rr < 2; ++rr) {
            const size_t so = (size_t)(t0 + arow + rr * 64) * HSZ + h0 + akc * 8;
            aH[rr] = *(const uint4*)(ahi + so);
            aM[rr] = *(const uint4*)(amd + so);
            aL[rr] = *(const uint4*)(alo + so);
        }
        #pragma unroll
        for (int rr = 0; rr < 2; ++rr) {
            const int kc = bkc0 + rr * 2;
            const float* wp = W + (size_t)(h0 + kc * 8) * HSZ + c0 + bcol;
            #pragma unroll
            for (int j = 0; j < 8; ++j) bx[rr][j] = wp[(size_t)j * HSZ];
        }
        __syncthreads();
        #pragma unroll
        for (int rr = 0; rr < 2; ++rr) {
            const int row = arow + rr * 64;
            *(uint4*)(Ah + row * 40 + akc * 8) = aH[rr];
            *(uint4*)(Am + row * 40 + akc * 8) = aM[rr];
            *(uint4*)(Al + row * 40 + akc * 8) = aL[rr];
        }
        #pragma unroll
        for (int rr = 0; rr < 2; ++rr) {
            const int kc = bkc0 + rr * 2;
            ushort hh[8], mm[8], ll[8];
            #pragma unroll
            for (int j = 0; j < 8; ++j) {
                float x = bx[rr][j];
                ushort h = f2bf(x);
                float r1 = x - bf2f(h);
                ushort m = f2bf(r1);
                hh[j] = h; mm[j] = m; ll[j] = f2bf(r1 - bf2f(m));
            }
            *(uint4*)(Bh + bcol * 40 + kc * 8) = pk8(hh);
            *(uint4*)(Bm + bcol * 40 + kc * 8) = pk8(mm);
            *(uint4*)(Bl + bcol * 40 + kc * 8) = pk8(ll);
        }
        __syncthreads();
        bf16x8 a1[4], a2[4], a3[4];
        #pragma unroll
        for (int i = 0; i < 4; ++i) {
            const int row = wrow * 64 + i * 16 + fr;
            a1[i] = *(const bf16x8*)(Ah + row * 40 + fg * 8);
            a2[i] = *(const bf16x8*)(Am + row * 40 + fg * 8);
            a3[i] = *(const bf16x8*)(Al + row * 40 + fg * 8);
        }
        #pragma unroll
        for (int j = 0; j < 4; ++j) {
            const int cr = wcol * 64 + j * 16 + fr;
            bf16x8 b1 = *(const bf16x8*)(Bh + cr * 40 + fg * 8);
            bf16x8 b2 = *(const bf16x8*)(Bm + cr * 40 + fg * 8);
            bf16x8 b3 = *(const bf16x8*)(Bl + cr * 40 + fg * 8);
            #pragma unroll
            for (int i = 0; i < 4; ++i) {
                acc[i][j] = __builtin_amdgcn_mfma_f32_16x16x32_bf16(a1[i], b1, acc[i][j], 0, 0, 0);
                acc[i][j] = __builtin_amdgcn_mfma_f32_16x16x32_bf16(a1[i], b2, acc[i][j], 0, 0, 0);
                acc[i][j] = __builtin_amdgcn_mfma_f32_16x16x32_bf16(a2[i], b1, acc[i][j], 0, 0, 0);
                acc[i][j] = __builtin_amdgcn_mfma_f32_16x16x32_bf16(a1[i], b3, acc[i][j], 0, 0, 0);
                acc[i][j] = __builtin_amdgcn_mfma_f32_16x16x32_bf16(a3[i], b1, acc[i][j], 0, 0, 0);
                acc[i][j] = __builtin_amdgcn_mfma_f32_16x16x32_bf16(a2[i], b2, acc[i][j], 0, 0, 0);
            }
        }
    }
    #pragma unroll
    for (int i = 0; i < 4; ++i)
        #pragma unroll
        for (int j = 0; j < 4; ++j)
            #pragma unroll
            for (int r = 0; r < 4; ++r) {
                const int trow = wrow * 64 + i * 16 + fg * 4 + r;
                const int dd   = wcol * 64 + j * 16 + fr;
                C[(size_t)(t0 + trow) * HSZ + c0 + dd] = acc[i][j][r];
            }
}

// ---------------------------------------------------------------------------
// pcpy_dot: out[t] = sum_k (C[t][k] + b[k]) * ctx[t][k]
// ---------------------------------------------------------------------------
__global__ __launch_bounds__(256) void pcpy_dot(
    const float* __restrict__ C, const float* __restrict__ ctx,
    const float* __restrict__ bc, float* __restrict__ out)
{
    const int t = blockIdx.x, tid = threadIdx.x;
    const float4 c4 = *(const float4*)(C + (size_t)t * HSZ + tid * 4);
    const float4 x4 = *(const float4*)(ctx + (size_t)t * HSZ + tid * 4);
    const float4 b4 = *(const float4*)(bc + tid * 4);
    float p = (c4.x + b4.x) * x4.x + (c4.y + b4.y) * x4.y
            + (c4.z + b4.z) * x4.z + (c4.w + b4.w) * x4.w;
    #pragma unroll
    for (int off = 32; off > 0; off >>= 1) p += __shfl_down(p, off, 64);
    __shared__ float r4[4];
    if ((tid & 63) == 0) r4[tid >> 6] = p;
    __syncthreads();
    if (tid == 0) out[t] = r4[0] + r4[1] + r4[2] + r4[3];
}

// ---------------------------------------------------------------------------
// head_mfma: fused logits GEMM (2-term split bf16, 3 MFMA passes) + bias +
// gumbel + exp + per-token {sum e, argmax s} + P@emb (bf16 MFMA).
// 128 tokens x 128 vocab cols per tile; 4 waves; partials to workspace.
// ---------------------------------------------------------------------------
__global__ __launch_bounds__(256, 2) void head_mfma(
    const ushort* __restrict__ ctx_hi, const ushort* __restrict__ ctx_lo,
    const float* __restrict__ W, const float* __restrict__ bias,
    const float* __restrict__ g, const float* __restrict__ emb,
    int V, int ldg, int tps, int n_tiles,
    float* __restrict__ wsW, float* __restrict__ wsBV,
    int* __restrict__ wsBI, float* __restrict__ wsE)
{
    // LDS map (ushort units): A/B staging 0..20479 (4 x 128x40)
    // aliased: P (exp tile bf16) 0..17407 [128][136]; EM (emb bf16) 17408..26623 [128][72]
    // stats (bytes): wsum @53248, bval @54272, bidx @55296  -> total 56320 B
    __shared__ __align__(16) char smem[56320];
    ushort* Ah = (ushort*)smem;
    ushort* Al = Ah + 5120;
    ushort* Bh = Ah + 10240;
    ushort* Bl = Ah + 15360;
    ushort* Pl = Ah;
    ushort* EM = Ah + 17408;
    float* sm_wsum = (float*)(smem + 53248);
    float* sm_bval = (float*)(smem + 54272);
    int*   sm_bidx = (int*)(smem + 55296);

    const int tid  = threadIdx.x;
    const int lane = tid & 63;
    const int fr   = lane & 15;
    const int fg   = lane >> 4;
    const int w    = tid >> 6;
    const int wrow = w >> 1;
    const int wcol = w & 1;
    const int t0   = blockIdx.x * 128;
    const int split = blockIdx.y;

    if (tid < 128) {
        sm_wsum[tid * 2] = 0.f;        sm_wsum[tid * 2 + 1] = 0.f;
        sm_bval[tid * 2] = -INFINITY;  sm_bval[tid * 2 + 1] = -INFINITY;
        sm_bidx[tid * 2] = 0;          sm_bidx[tid * 2 + 1] = 0;
    }

    f32x4 zero4 = {0.f, 0.f, 0.f, 0.f};
    f32x4 Eacc[4][4];
    #pragma unroll
    for (int i = 0; i < 4; ++i)
        #pragma unroll
        for (int j = 0; j < 4; ++j) Eacc[i][j] = zero4;

    int tbeg = split * tps;
    int tend = tbeg + tps; if (tend > n_tiles) tend = n_tiles;

    const int arow = tid >> 2, akc = tid & 3;
    const int bcol = tid & 127, bkc0 = tid >> 7;

    for (int tt = tbeg; tt < tend; ++tt) {
        const int c0 = tt * 128;
        f32x4 acc[4][4];
        #pragma unroll
        for (int i = 0; i < 4; ++i)
            #pragma unroll
            for (int j = 0; j < 4; ++j) acc[i][j] = zero4;

        for (int h0 = 0; h0 < HSZ; h0 += 32) {
            uint4 aH[2], aL[2];
            float bx[2][8];
            #pragma unroll
            for (int rr = 0; rr < 2; ++rr) {
                const size_t so = (size_t)(t0 + arow + rr * 64) * HSZ + h0 + akc * 8;
                aH[rr] = *(const uint4*)(ctx_hi + so);
                aL[rr] = *(const uint4*)(ctx_lo + so);
            }
            #pragma unroll
            for (int rr = 0; rr < 2; ++rr) {
                const int kc = bkc0 + rr * 2;
                const int gc = c0 + bcol;
                const float* wp = W + (size_t)(h0 + kc * 8) * V + gc;
                const bool vld = (gc < V);
                #pragma unroll
                for (int j = 0; j < 8; ++j) bx[rr][j] = vld ? wp[(size_t)j * V] : 0.f;
            }
            __syncthreads();
            #pragma unroll
            for (int rr = 0; rr < 2; ++rr) {
                const int row = arow + rr * 64;
                *(uint4*)(Ah + row * 40 + akc * 8) = aH[rr];
                *(uint4*)(Al + row * 40 + akc * 8) = aL[rr];
            }
            #pragma unroll
            for (int rr = 0; rr < 2; ++rr) {
                const int kc = bkc0 + rr * 2;
                ushort hh[8], ll[8];
                #pragma unroll
                for (int j = 0; j < 8; ++j) {
                    float x = bx[rr][j];
                    ushort h = f2bf(x);
                    hh[j] = h;
                    ll[j] = f2bf(x - bf2f(h));
                }
                *(uint4*)(Bh + bcol * 40 + kc * 8) = pk8(hh);
                *(uint4*)(Bl + bcol * 40 + kc * 8) = pk8(ll);
            }
            __syncthreads();
            bf16x8 ah[4], al[4];
            #pragma unroll
            for (int i = 0; i < 4; ++i) {
                const int row = wrow * 64 + i * 16 + fr;
                ah[i] = *(const bf16x8*)(Ah + row * 40 + fg * 8);
                al[i] = *(const bf16x8*)(Al + row * 40 + fg * 8);
            }
            #pragma unroll
            for (int j = 0; j < 4; ++j) {
                const int cr = wcol * 64 + j * 16 + fr;
                bf16x8 vbh = *(const bf16x8*)(Bh + cr * 40 + fg * 8);
                bf16x8 vbl = *(const bf16x8*)(Bl + cr * 40 + fg * 8);
                #pragma unroll
                for (int i = 0; i < 4; ++i) {
                    acc[i][j] = __builtin_amdgcn_mfma_f32_16x16x32_bf16(ah[i], vbh, acc[i][j], 0, 0, 0);
                    acc[i][j] = __builtin_amdgcn_mfma_f32_16x16x32_bf16(ah[i], vbl, acc[i][j], 0, 0, 0);
                    acc[i][j] = __builtin_amdgcn_mfma_f32_16x16x32_bf16(al[i], vbh, acc[i][j], 0, 0, 0);
                }
            }
        }
        __syncthreads();  // A/B staging dead; region reused for P

        // ---- bias + gumbel + exp, P -> LDS (bf16), per-token stats ----
        float bias4[4];
        #pragma unroll
        for (int j = 0; j < 4; ++j) {
            const int gc = c0 + wcol * 64 + j * 16 + fr;
            bias4[j] = (gc < V) ? bias[gc] : 0.f;
        }
        #pragma unroll
        for (int i = 0; i < 4; ++i) {
            #pragma unroll
            for (int r = 0; r < 4; ++r) {
                const int trow = wrow * 64 + i * 16 + fg * 4 + r;
                const float* gp = g + (size_t)(t0 + trow) * ldg + c0 + wcol * 64 + fr;
                float esum = 0.f, mx = -INFINITY;
                int mi = 0;
                #pragma unroll
                for (int j = 0; j < 4; ++j) {
                    const int gc = c0 + wcol * 64 + j * 16 + fr;
                    float e = 0.f;
                    if (gc < V) {
                        const float s = acc[i][j][r] + bias4[j] + gp[j * 16];
                        e = __expf(s);
                        esum += e;
                        if (s > mx) { mx = s; mi = gc; }
                    }
                    Pl[trow * 136 + wcol * 64 + j * 16 + fr] = f2bf(e);
                }
                #pragma unroll
                for (int off = 1; off < 16; off <<= 1) {
                    const float ov = __shfl_xor(mx, off, 64);
                    const int   oi = __shfl_xor(mi, off, 64);
                    esum += __shfl_xor(esum, off, 64);
                    if (ov > mx || (ov == mx && oi < mi)) { mx = ov; mi = oi; }
                }
                if (fr == 0) {
                    sm_wsum[trow * 2 + wcol] += esum;
                    const float cb = sm_bval[trow * 2 + wcol];
                    const int   ci = sm_bidx[trow * 2 + wcol];
                    if (mx > cb || (mx == cb && mi < ci)) {
                        sm_bval[trow * 2 + wcol] = mx;
                        sm_bidx[trow * 2 + wcol] = mi;
                    }
                }
            }
        }

        // ---- E-GEMM in two 64-col halves (EM buffer holds 64 cols) ----
        #pragma unroll
        for (int hf = 0; hf < 2; ++hf) {
            __syncthreads();  // P/prev-EM reads done; stage this half's emb
            #pragma unroll
            for (int rr = 0; rr < 4; ++rr) {
                const int task = tid + rr * 256;
                const int d = task & 127;
                const int cc = task >> 7;  // 0..7
                ushort o8[8];
                #pragma unroll
                for (int j = 0; j < 8; ++j) {
                    const int gc = c0 + hf * 64 + cc * 8 + j;
                    o8[j] = (gc < V) ? f2bf(emb[(size_t)gc * DIM + d]) : (ushort)0;
                }
                *(uint4*)(EM + d * 72 + cc * 8) = pk8(o8);
            }
            __syncthreads();
            #pragma unroll
            for (int ks = 0; ks < 2; ++ks) {
                bf16x8 ap[4];
                #pragma unroll
                for (int i = 0; i < 4; ++i) {
                    const int row = wrow * 64 + i * 16 + fr;
                    ap[i] = *(const bf16x8*)(Pl + row * 136 + hf * 64 + ks * 32 + fg * 8);
                }
                #pragma unroll
                for (int j = 0; j < 4; ++j) {
                    const int dd = wcol * 64 + j * 16 + fr;
                    bf16x8 eb = *(const bf16x8*)(EM + dd * 72 + ks * 32 + fg * 8);
                    #pragma unroll
                    for (int i = 0; i < 4; ++i)
                        Eacc[i][j] = __builtin_amdgcn_mfma_f32_16x16x32_bf16(ap[i], eb, Eacc[i][j], 0, 0, 0);
                }
            }
        }
        __syncthreads();  // EM/P reads done before next tile's staging
    }

    __syncthreads();
    if (tid < 128) {
        const float wsv = sm_wsum[tid * 2] + sm_wsum[tid * 2 + 1];
        const float b0 = sm_bval[tid * 2], b1 = sm_bval[tid * 2 + 1];
        const int   i0 = sm_bidx[tid * 2], i1 = sm_bidx[tid * 2 + 1];
        float bv; int bi;
        if (b0 > b1 || (b0 == b1 && i0 < i1)) { bv = b0; bi = i0; }
        else                                   { bv = b1; bi = i1; }
        const size_t o = (size_t)split * TOK + t0 + tid;
        wsW[o] = wsv; wsBV[o] = bv; wsBI[o] = bi;
    }
    #pragma unroll
    for (int i = 0; i < 4; ++i)
        #pragma unroll
        for (int j = 0; j < 4; ++j)
            #pragma unroll
            for (int r = 0; r < 4; ++r) {
                const int trow = wrow * 64 + i * 16 + fg * 4 + r;
                const int dd   = wcol * 64 + j * 16 + fr;
                wsE[((size_t)split * TOK + t0 + trow) * DIM + dd] = Eacc[i][j][r];
            }
}

// ---------------------------------------------------------------------------
// Combine: merge partials, add copy column, pick words, select outputs.
// ---------------------------------------------------------------------------
__global__ __launch_bounds__(128) void combine_kernel(
    const int* __restrict__ inp_word, const float* __restrict__ masks,
    const int* __restrict__ spt_mask, const int* __restrict__ tgt_ids,
    const float* __restrict__ word_emb, const float* __restrict__ pcpy,
    const float* __restrict__ g_nrm,
    const float* __restrict__ nW, const float* __restrict__ nBV,
    const int* __restrict__ nBI, const float* __restrict__ nE, int NVn,
    const float* __restrict__ sW, const float* __restrict__ sBV,
    const int* __restrict__ sBI, const float* __restrict__ sE, int NVs,
    float* __restrict__ out)
{
    const int t = (int)blockIdx.x;
    const int d = (int)threadIdx.x;

    float Wn = 0.f, En = 0.f, bv = -INFINITY; int bi = 0;
    for (int v = 0; v < NVn; ++v) {
        const size_t o = (size_t)v * TOK + t;
        Wn += nW[o];
        En += nE[o * DIM + d];
        const float vv = nBV[o]; const int ii = nBI[o];
        if (vv > bv || (vv == bv && ii < bi)) { bv = vv; bi = ii; }
    }
    const int iw = inp_word[t];
    const float sc = pcpy[t] + g_nrm[(size_t)t * (NWRDC + 1) + NWRDC];
    const float ec = __expf(sc);
    Wn += ec;
    En += ec * word_emb[(size_t)iw * DIM + d];
    const int ynrm = (sc > bv) ? iw : bi;

    float Ws = 0.f, Ese = 0.f, sv = -INFINITY; int si = 0;
    for (int v = 0; v < NVs; ++v) {
        const size_t o = (size_t)v * TOK + t;
        Ws += sW[o];
        Ese += sE[o * DIM + d];
        const float vv = sBV[o]; const int ii = sBI[o];
        if (vv > sv || (vv == sv && ii < si)) { sv = vv; si = ii; }
    }
    const int yspt = tgt_ids[si];

    const float sptf = (float)spt_mask[t];
    const float nrmf = (1.f - sptf) * masks[t];

    float eo; int obf;
    if (sptf > 0.f)      { eo = Ese / Ws; obf = yspt; }
    else if (nrmf > 0.f) { eo = En / Wn;  obf = ynrm; }
    else                 { obf = iw; eo = word_emb[(size_t)iw * DIM + d]; }

    out[(size_t)t * DIM + d] = eo;
    if (d == 0) {
        out[(size_t)TOK * DIM + t]       = (float)obf;
        out[(size_t)TOK * DIM + TOK + t] = sptf;
    }
}

// ---------------------------------------------------------------------------
extern "C" void kernel_launch(void* const* d_in, const int* in_sizes, int n_in,
                              void* d_out, int out_size, void* d_ws, size_t ws_size,
                              hipStream_t stream)
{
    const int*   inp_word = (const int*)d_in[0];
    const float* masks    = (const float*)d_in[1];
    const int*   spt_mask = (const int*)d_in[2];
    const int*   tgt_ids  = (const int*)d_in[3];
    const float* ctx      = (const float*)d_in[4];
    const float* W_spt    = (const float*)d_in[5];
    const float* b_spt    = (const float*)d_in[6];
    const float* W_nrm    = (const float*)d_in[7];
    const float* b_nrm    = (const float*)d_in[8];
    const float* W_cpy    = (const float*)d_in[9];
    const float* b_cpy    = (const float*)d_in[10];
    const float* word_emb = (const float*)d_in[11];
    const float* word_emb_tgt = (const float*)d_in[12];
    const float* g_spt    = (const float*)d_in[13];
    const float* g_nrm    = (const float*)d_in[14];
    float* out = (float*)d_out;

    // ---- workspace carve (bytes) ----
    char* wsb = (char*)d_ws;
    float*  pcpy = (float*)wsb;                              // 4 KB
    ushort* ctxh = (ushort*)(wsb + 4096);                    // 2 MB
    ushort* ctxm = (ushort*)(wsb + 4096 + 2097152);          // 2 MB
    ushort* ctxl = (ushort*)(wsb + 4096 + 4194304);          // 2 MB
    char*   region = wsb + 4096 + 6291456;                   // 6295552
    float*  Cws = (float*)region;                            // 4 MB, dead after pcpy_dot

    const size_t per_split = (size_t)TOK * (DIM + 3) * 4;    // 536576 B
    long nsp = 0;
    if (ws_size > 6295552 + per_split) nsp = (long)((ws_size - 6295552) / per_split);
    int NVs = (int)(nsp / 5); if (NVs < 1) NVs = 1; if (NVs > 16) NVs = 16;
    long rem = nsp - NVs;
    int NVn = (int)rem; if (NVn < 1) NVn = 1; if (NVn > 64) NVn = 64;

    float* nW  = (float*)region;
    float* nBV = nW + (size_t)NVn * TOK;
    int*   nBI = (int*)(nBV + (size_t)NVn * TOK);
    float* nE  = (float*)(nBI + (size_t)NVn * TOK);
    float* sW  = nE + (size_t)NVn * TOK * DIM;
    float* sBV = sW + (size_t)NVs * TOK;
    int*   sBI = (int*)(sBV + (size_t)NVs * TOK);
    float* sE  = (float*)(sBI + (size_t)NVs * TOK);

    const int ntile_n = NWRDC / 128;                         // 250
    const int tps_n = (ntile_n + NVn - 1) / NVn;
    const int ntile_s = (NTGTC + 127) / 128;                 // 16
    const int tps_s = (ntile_s + NVs - 1) / NVs;

    split_ctx3<<<dim3(TOK * HSZ / 1024), dim3(256), 0, stream>>>(ctx, ctxh, ctxm, ctxl);
    gemm_cpy<<<dim3(8, 8), dim3(256), 0, stream>>>(ctxh, ctxm, ctxl, W_cpy, Cws);
    pcpy_dot<<<dim3(TOK), dim3(256), 0, stream>>>(Cws, ctx, b_cpy, pcpy);
    head_mfma<<<dim3(8, NVn), dim3(256), 0, stream>>>(
        ctxh, ctxm, W_nrm, b_nrm, g_nrm, word_emb, NWRDC, NWRDC + 1,
        tps_n, ntile_n, nW, nBV, nBI, nE);
    head_mfma<<<dim3(8, NVs), dim3(256), 0, stream>>>(
        ctxh, ctxm, W_spt, b_spt, g_spt, word_emb_tgt, NTGTC, NTGTC,
        tps_s, ntile_s, sW, sBV, sBI, sE);
    combine_kernel<<<dim3(TOK), dim3(128), 0, stream>>>(
        inp_word, masks, spt_mask, tgt_ids, word_emb, pcpy, g_nrm,
        nW, nBV, nBI, nE, NVn, sW, sBV, sBI, sE, NVs, out);
    (void)in_sizes; (void)n_in; (void)out_size;
}

// Round 4
// 827.716 us; speedup vs baseline: 4.0278x; 1.0845x over previous
//
#include <hip/hip_runtime.h>
#include <math.h>

#define TOK   1024
#define HSZ   1024
#define DIM   128
#define NWRDC 32000
#define NTGTC 2000

typedef __attribute__((ext_vector_type(8))) short bf16x8;
typedef __attribute__((ext_vector_type(4))) float f32x4;

__device__ __forceinline__ ushort f2bf(float x) {
    union { float f; uint u; } c; c.f = x;
    return (ushort)((c.u + 0x7fffu + ((c.u >> 16) & 1u)) >> 16);
}
__device__ __forceinline__ float bf2f(ushort h) {
    union { uint u; float f; } c; c.u = ((uint)h) << 16;
    return c.f;
}
__device__ __forceinline__ uint4 pk8(const ushort v[8]) {
    uint4 u;
    u.x = (uint)v[0] | ((uint)v[1] << 16);
    u.y = (uint)v[2] | ((uint)v[3] << 16);
    u.z = (uint)v[4] | ((uint)v[5] << 16);
    u.w = (uint)v[6] | ((uint)v[7] << 16);
    return u;
}

#define GLL16(SRC, DST) __builtin_amdgcn_global_load_lds( \
    (const __attribute__((address_space(1))) void*)(SRC), \
    (__attribute__((address_space(3))) void*)(DST), 16, 0, 0)

// ---------------------------------------------------------------------------
// split ctx into 3 bf16 terms (natural [tok][1024] layout)
// ---------------------------------------------------------------------------
__global__ __launch_bounds__(256) void split_ctx3(
    const float* __restrict__ x, ushort* __restrict__ hp,
    ushort* __restrict__ mp, ushort* __restrict__ lp)
{
    const int i4 = (blockIdx.x * 256 + threadIdx.x) * 4;
    float4 v = *(const float4*)(x + i4);
    float xs[4] = {v.x, v.y, v.z, v.w};
    ushort hh[4], mm[4], ll[4];
    #pragma unroll
    for (int k = 0; k < 4; ++k) {
        ushort h = f2bf(xs[k]);
        float r1 = xs[k] - bf2f(h);
        ushort m = f2bf(r1);
        ushort l = f2bf(r1 - bf2f(m));
        hh[k] = h; mm[k] = m; ll[k] = l;
    }
    uint2 u;
    u.x = (uint)hh[0] | ((uint)hh[1] << 16); u.y = (uint)hh[2] | ((uint)hh[3] << 16);
    *(uint2*)(hp + i4) = u;
    u.x = (uint)mm[0] | ((uint)mm[1] << 16); u.y = (uint)mm[2] | ((uint)mm[3] << 16);
    *(uint2*)(mp + i4) = u;
    u.x = (uint)ll[0] | ((uint)ll[1] << 16); u.y = (uint)ll[2] | ((uint)ll[3] << 16);
    *(uint2*)(lp + i4) = u;
}

// ---------------------------------------------------------------------------
// gemm_cpy: C = ctx @ W_cpy (3-term split, 6 passes) -- unchanged
// ---------------------------------------------------------------------------
__global__ __launch_bounds__(256, 2) void gemm_cpy(
    const ushort* __restrict__ ahi, const ushort* __restrict__ amd,
    const ushort* __restrict__ alo, const float* __restrict__ W,
    float* __restrict__ C)
{
    __shared__ __align__(16) ushort sm[30720];
    ushort* Ah = sm;
    ushort* Am = sm + 5120;
    ushort* Al = sm + 10240;
    ushort* Bh = sm + 15360;
    ushort* Bm = sm + 20480;
    ushort* Bl = sm + 25600;

    const int tid  = threadIdx.x;
    const int lane = tid & 63;
    const int fr   = lane & 15;
    const int fg   = lane >> 4;
    const int w    = tid >> 6;
    const int wrow = w >> 1;
    const int wcol = w & 1;
    const int t0   = blockIdx.x * 128;
    const int c0   = blockIdx.y * 128;

    const int arow = tid >> 2, akc = tid & 3;
    const int bcol = tid & 127, bkc0 = tid >> 7;

    f32x4 zero4 = {0.f, 0.f, 0.f, 0.f};
    f32x4 acc[4][4];
    #pragma unroll
    for (int i = 0; i < 4; ++i)
        #pragma unroll
        for (int j = 0; j < 4; ++j) acc[i][j] = zero4;

    for (int h0 = 0; h0 < HSZ; h0 += 32) {
        uint4 aH[2], aM[2], aL[2];
        float bx[2][8];
        #pragma unroll
        for (int rr = 0; rr < 2; ++rr) {
            const size_t so = (size_t)(t0 + arow + rr * 64) * HSZ + h0 + akc * 8;
            aH[rr] = *(const uint4*)(ahi + so);
            aM[rr] = *(const uint4*)(amd + so);
            aL[rr] = *(const uint4*)(alo + so);
        }
        #pragma unroll
        for (int rr = 0; rr < 2; ++rr) {
            const int kc = bkc0 + rr * 2;
            const float* wp = W + (size_t)(h0 + kc * 8) * HSZ + c0 + bcol;
            #pragma unroll
            for (int j = 0; j < 8; ++j) bx[rr][j] = wp[(size_t)j * HSZ];
        }
        __syncthreads();
        #pragma unroll
        for (int rr = 0; rr < 2; ++rr) {
            const int row = arow + rr * 64;
            *(uint4*)(Ah + row * 40 + akc * 8) = aH[rr];
            *(uint4*)(Am + row * 40 + akc * 8) = aM[rr];
            *(uint4*)(Al + row * 40 + akc * 8) = aL[rr];
        }
        #pragma unroll
        for (int rr = 0; rr < 2; ++rr) {
            const int kc = bkc0 + rr * 2;
            ushort hh[8], mm[8], ll[8];
            #pragma unroll
            for (int j = 0; j < 8; ++j) {
                float x = bx[rr][j];
                ushort h = f2bf(x);
                float r1 = x - bf2f(h);
                ushort m = f2bf(r1);
                hh[j] = h; mm[j] = m; ll[j] = f2bf(r1 - bf2f(m));
            }
            *(uint4*)(Bh + bcol * 40 + kc * 8) = pk8(hh);
            *(uint4*)(Bm + bcol * 40 + kc * 8) = pk8(mm);
            *(uint4*)(Bl + bcol * 40 + kc * 8) = pk8(ll);
        }
        __syncthreads();
        bf16x8 a1[4], a2[4], a3[4];
        #pragma unroll
        for (int i = 0; i < 4; ++i) {
            const int row = wrow * 64 + i * 16 + fr;
            a1[i] = *(const bf16x8*)(Ah + row * 40 + fg * 8);
            a2[i] = *(const bf16x8*)(Am + row * 40 + fg * 8);
            a3[i] = *(const bf16x8*)(Al + row * 40 + fg * 8);
        }
        #pragma unroll
        for (int j = 0; j < 4; ++j) {
            const int cr = wcol * 64 + j * 16 + fr;
            bf16x8 b1 = *(const bf16x8*)(Bh + cr * 40 + fg * 8);
            bf16x8 b2 = *(const bf16x8*)(Bm + cr * 40 + fg * 8);
            bf16x8 b3 = *(const bf16x8*)(Bl + cr * 40 + fg * 8);
            #pragma unroll
            for (int i = 0; i < 4; ++i) {
                acc[i][j] = __builtin_amdgcn_mfma_f32_16x16x32_bf16(a1[i], b1, acc[i][j], 0, 0, 0);
                acc[i][j] = __builtin_amdgcn_mfma_f32_16x16x32_bf16(a1[i], b2, acc[i][j], 0, 0, 0);
                acc[i][j] = __builtin_amdgcn_mfma_f32_16x16x32_bf16(a2[i], b1, acc[i][j], 0, 0, 0);
                acc[i][j] = __builtin_amdgcn_mfma_f32_16x16x32_bf16(a1[i], b3, acc[i][j], 0, 0, 0);
                acc[i][j] = __builtin_amdgcn_mfma_f32_16x16x32_bf16(a3[i], b1, acc[i][j], 0, 0, 0);
                acc[i][j] = __builtin_amdgcn_mfma_f32_16x16x32_bf16(a2[i], b2, acc[i][j], 0, 0, 0);
            }
        }
    }
    #pragma unroll
    for (int i = 0; i < 4; ++i)
        #pragma unroll
        for (int j = 0; j < 4; ++j)
            #pragma unroll
            for (int r = 0; r < 4; ++r) {
                const int trow = wrow * 64 + i * 16 + fg * 4 + r;
                const int dd   = wcol * 64 + j * 16 + fr;
                C[(size_t)(t0 + trow) * HSZ + c0 + dd] = acc[i][j][r];
            }
}

// ---------------------------------------------------------------------------
__global__ __launch_bounds__(256) void pcpy_dot(
    const float* __restrict__ C, const float* __restrict__ ctx,
    const float* __restrict__ bc, float* __restrict__ out)
{
    const int t = blockIdx.x, tid = threadIdx.x;
    const float4 c4 = *(const float4*)(C + (size_t)t * HSZ + tid * 4);
    const float4 x4 = *(const float4*)(ctx + (size_t)t * HSZ + tid * 4);
    const float4 b4 = *(const float4*)(bc + tid * 4);
    float p = (c4.x + b4.x) * x4.x + (c4.y + b4.y) * x4.y
            + (c4.z + b4.z) * x4.z + (c4.w + b4.w) * x4.w;
    #pragma unroll
    for (int off = 32; off > 0; off >>= 1) p += __shfl_down(p, off, 64);
    __shared__ float r4[4];
    if ((tid & 63) == 0) r4[tid >> 6] = p;
    __syncthreads();
    if (tid == 0) out[t] = r4[0] + r4[1] + r4[2] + r4[3];
}

// ---------------------------------------------------------------------------
// head_mfma v3: A staged via global_load_lds (double-buffered), W staged via
// coalesced float4 + pipelined convert, pair-interleaved XOR-swizzled LDS.
// LDS map (bytes): Ah0@0 Al0@8192 Ah1@16384 Al1@24576 Bh@32768 Bl@40960
//   epilogue alias: P@0 [128][136]us, EM@34816 [128][72]us
//   stats: wsum@53248 bval@54272 bidx@55296 -> total 56320
// LDS element (row,k) at pair=row>>1, chunk'=(((row&1)<<2)|(k>>3))^(pair&7):
//   byte = pair*128 + chunk'*16 + (k&7)*2
// ---------------------------------------------------------------------------
__global__ __launch_bounds__(256, 2) void head_mfma(
    const ushort* __restrict__ ctx_hi, const ushort* __restrict__ ctx_lo,
    const float* __restrict__ W, const float* __restrict__ bias,
    const float* __restrict__ g, const float* __restrict__ emb,
    int V, int ldg, int tps, int n_tiles,
    float* __restrict__ wsW, float* __restrict__ wsBV,
    int* __restrict__ wsBI, float* __restrict__ wsE)
{
    __shared__ __align__(16) char smem[56320];
    ushort* Pl = (ushort*)smem;
    ushort* EM = (ushort*)(smem + 34816);
    float* sm_wsum = (float*)(smem + 53248);
    float* sm_bval = (float*)(smem + 54272);
    int*   sm_bidx = (int*)(smem + 55296);

    const int tid  = threadIdx.x;
    const int lane = tid & 63;
    const int fr   = lane & 15;
    const int fg   = lane >> 4;
    const int wv   = tid >> 6;
    const int wrow = wv >> 1;
    const int wcol = wv & 1;
    const int split = (int)blockIdx.x;
    const int t0    = (int)blockIdx.y * 128;

    if (tid < 128) {
        sm_wsum[tid * 2] = 0.f;        sm_wsum[tid * 2 + 1] = 0.f;
        sm_bval[tid * 2] = -INFINITY;  sm_bval[tid * 2 + 1] = -INFINITY;
        sm_bidx[tid * 2] = 0;          sm_bidx[tid * 2 + 1] = 0;
    }

    // fragment-read lane constants (2-way-free swizzle)
    const int chunkRd  = (((fr & 1) << 2) | fg) ^ ((fr >> 1) & 7);
    const int laneAoff = wrow * 4096 + (fr >> 1) * 128 + chunkRd * 16;
    const int laneBoff = wcol * 4096 + (fr >> 1) * 128 + chunkRd * 16;

    // global_load_lds lane constants
    const int cfA   = (lane & 7) ^ (lane >> 3);
    const int glTok = (wv * 8 + (lane >> 3)) * 2 + (cfA >> 2);
    const int glK   = (cfA & 3) * 8;
    const int glDst = wv * 1024;

    // W staging constants: thread covers cols c4..c4+3, rows hb,hb+1,hb+16,hb+17
    const int c4 = (tid & 31) * 4;
    const int hb = (tid >> 5) * 2;
    int wb01[4], wb23[4];
    #pragma unroll
    for (int i = 0; i < 4; ++i) {
        const int col = c4 + i;
        const int pair = col >> 1;
        const int ch01 = (((col & 1) << 2) | (hb >> 3)) ^ (pair & 7);
        const int ch23 = (((col & 1) << 2) | (2 + (hb >> 3))) ^ (pair & 7);
        wb01[i] = pair * 128 + ch01 * 16 + (hb & 7) * 2;
        wb23[i] = pair * 128 + ch23 * 16 + (hb & 7) * 2;
    }

    f32x4 zero4 = {0.f, 0.f, 0.f, 0.f};
    f32x4 Eacc[4][4];
    #pragma unroll
    for (int i = 0; i < 4; ++i)
        #pragma unroll
        for (int j = 0; j < 4; ++j) Eacc[i][j] = zero4;

    int tbeg = split * tps;
    int tend = tbeg + tps; if (tend > n_tiles) tend = n_tiles;

    #define STAGE_A(STEP, BASE) do {                                              \
        const size_t ro_ = (size_t)(t0 + glTok) * HSZ + (size_t)(STEP) * 32 + glK; \
        GLL16(ctx_hi + ro_,          (BASE) + glDst);                              \
        GLL16(ctx_hi + ro_ + 65536,  (BASE) + 4096 + glDst);                       \
        GLL16(ctx_lo + ro_,          (BASE) + 8192 + glDst);                       \
        GLL16(ctx_lo + ro_ + 65536,  (BASE) + 12288 + glDst);                      \
    } while (0)

    #define LOAD_W(STEP, VV) do {                                                 \
        const int gc_ = c0 + c4;                                                  \
        if (gc_ + 3 < V) {                                                        \
            const float* p_ = W + (size_t)((STEP) * 32 + hb) * V + gc_;           \
            VV[0] = *(const float4*)p_;                                           \
            VV[1] = *(const float4*)(p_ + V);                                     \
            VV[2] = *(const float4*)(p_ + 16 * (size_t)V);                        \
            VV[3] = *(const float4*)(p_ + 17 * (size_t)V);                        \
        } else {                                                                  \
            float4 z_ = {0.f, 0.f, 0.f, 0.f};                                     \
            VV[0] = z_; VV[1] = z_; VV[2] = z_; VV[3] = z_;                       \
        }                                                                         \
    } while (0)

    #define CONV_W(VV) do {                                                       \
        _Pragma("unroll")                                                         \
        for (int i_ = 0; i_ < 4; ++i_) {                                          \
            const float* fv0 = (const float*)&VV[0];                              \
            const float* fv1 = (const float*)&VV[1];                              \
            const float* fv2 = (const float*)&VV[2];                              \
            const float* fv3 = (const float*)&VV[3];                              \
            float a0 = fv0[i_], a1 = fv1[i_], a2 = fv2[i_], a3 = fv3[i_];         \
            ushort h0b = f2bf(a0); ushort l0b = f2bf(a0 - bf2f(h0b));             \
            ushort h1b = f2bf(a1); ushort l1b = f2bf(a1 - bf2f(h1b));             \
            ushort h2b = f2bf(a2); ushort l2b = f2bf(a2 - bf2f(h2b));             \
            ushort h3b = f2bf(a3); ushort l3b = f2bf(a3 - bf2f(h3b));             \
            *(uint*)(smem + 32768 + wb01[i_]) = (uint)h0b | ((uint)h1b << 16);    \
            *(uint*)(smem + 32768 + wb23[i_]) = (uint)h2b | ((uint)h3b << 16);    \
            *(uint*)(smem + 40960 + wb01[i_]) = (uint)l0b | ((uint)l1b << 16);    \
            *(uint*)(smem + 40960 + wb23[i_]) = (uint)l2b | ((uint)l3b << 16);    \
        }                                                                         \
    } while (0)

    for (int tt = tbeg; tt < tend; ++tt) {
        const int c0 = tt * 128;
        f32x4 acc[4][4];
        #pragma unroll
        for (int i = 0; i < 4; ++i)
            #pragma unroll
            for (int j = 0; j < 4; ++j) acc[i][j] = zero4;

        // prologue: stage step 0
        STAGE_A(0, smem);
        {
            float4 v0[4];
            LOAD_W(0, v0);
            CONV_W(v0);
        }
        __syncthreads();

        for (int ks = 0; ks < 32; ++ks) {
            const int cur = ks & 1;
            const bool more = (ks + 1) < 32;
            float4 vn[4];
            if (more) {
                STAGE_A(ks + 1, smem + (cur ^ 1) * 16384);
                LOAD_W(ks + 1, vn);
            }
            char* bA = smem + cur * 16384;
            bf16x8 ah[4], al[4];
            #pragma unroll
            for (int i = 0; i < 4; ++i) {
                ah[i] = *(const bf16x8*)(bA + laneAoff + i * 1024);
                al[i] = *(const bf16x8*)(bA + 8192 + laneAoff + i * 1024);
            }
            #pragma unroll
            for (int j = 0; j < 4; ++j) {
                bf16x8 vbh = *(const bf16x8*)(smem + 32768 + laneBoff + j * 1024);
                bf16x8 vbl = *(const bf16x8*)(smem + 40960 + laneBoff + j * 1024);
                #pragma unroll
                for (int i = 0; i < 4; ++i) {
                    acc[i][j] = __builtin_amdgcn_mfma_f32_16x16x32_bf16(ah[i], vbh, acc[i][j], 0, 0, 0);
                    acc[i][j] = __builtin_amdgcn_mfma_f32_16x16x32_bf16(ah[i], vbl, acc[i][j], 0, 0, 0);
                    acc[i][j] = __builtin_amdgcn_mfma_f32_16x16x32_bf16(al[i], vbh, acc[i][j], 0, 0, 0);
                }
            }
            __syncthreads();   // B reads of step ks complete
            if (more) {
                CONV_W(vn);
            }
            __syncthreads();   // B (and staged A) ready for next step
        }

        // ---- epilogue: bias + gumbel + exp, P -> LDS (bf16), stats ----
        float bias4[4];
        #pragma unroll
        for (int j = 0; j < 4; ++j) {
            const int gc = c0 + wcol * 64 + j * 16 + fr;
            bias4[j] = (gc < V) ? bias[gc] : 0.f;
        }
        #pragma unroll
        for (int i = 0; i < 4; ++i) {
            #pragma unroll
            for (int r = 0; r < 4; ++r) {
                const int trow = wrow * 64 + i * 16 + fg * 4 + r;
                const float* gp = g + (size_t)(t0 + trow) * ldg + c0 + wcol * 64 + fr;
                float esum = 0.f, mx = -INFINITY;
                int mi = 0;
                #pragma unroll
                for (int j = 0; j < 4; ++j) {
                    const int gc = c0 + wcol * 64 + j * 16 + fr;
                    float e = 0.f;
                    if (gc < V) {
                        const float s = acc[i][j][r] + bias4[j] + gp[j * 16];
                        e = __expf(s);
                        esum += e;
                        if (s > mx) { mx = s; mi = gc; }
                    }
                    Pl[trow * 136 + wcol * 64 + j * 16 + fr] = f2bf(e);
                }
                #pragma unroll
                for (int off = 1; off < 16; off <<= 1) {
                    const float ov = __shfl_xor(mx, off, 64);
                    const int   oi = __shfl_xor(mi, off, 64);
                    esum += __shfl_xor(esum, off, 64);
                    if (ov > mx || (ov == mx && oi < mi)) { mx = ov; mi = oi; }
                }
                if (fr == 0) {
                    sm_wsum[trow * 2 + wcol] += esum;
                    const float cb = sm_bval[trow * 2 + wcol];
                    const int   ci = sm_bidx[trow * 2 + wcol];
                    if (mx > cb || (mx == cb && mi < ci)) {
                        sm_bval[trow * 2 + wcol] = mx;
                        sm_bidx[trow * 2 + wcol] = mi;
                    }
                }
            }
        }

        // ---- E-GEMM in two 64-col halves ----
        #pragma unroll
        for (int hf = 0; hf < 2; ++hf) {
            __syncthreads();
            #pragma unroll
            for (int rr = 0; rr < 4; ++rr) {
                const int task = tid + rr * 256;
                const int d = task & 127;
                const int cc = task >> 7;
                ushort o8[8];
                #pragma unroll
                for (int j = 0; j < 8; ++j) {
                    const int gc = c0 + hf * 64 + cc * 8 + j;
                    o8[j] = (gc < V) ? f2bf(emb[(size_t)gc * DIM + d]) : (ushort)0;
                }
                *(uint4*)(EM + d * 72 + cc * 8) = pk8(o8);
            }
            __syncthreads();
            #pragma unroll
            for (int ksb = 0; ksb < 2; ++ksb) {
                bf16x8 ap[4];
                #pragma unroll
                for (int i = 0; i < 4; ++i) {
                    const int row = wrow * 64 + i * 16 + fr;
                    ap[i] = *(const bf16x8*)(Pl + row * 136 + hf * 64 + ksb * 32 + fg * 8);
                }
                #pragma unroll
                for (int j = 0; j < 4; ++j) {
                    const int dd = wcol * 64 + j * 16 + fr;
                    bf16x8 eb = *(const bf16x8*)(EM + dd * 72 + ksb * 32 + fg * 8);
                    #pragma unroll
                    for (int i = 0; i < 4; ++i)
                        Eacc[i][j] = __builtin_amdgcn_mfma_f32_16x16x32_bf16(ap[i], eb, Eacc[i][j], 0, 0, 0);
                }
            }
        }
        __syncthreads();
    }

    __syncthreads();
    if (tid < 128) {
        const float wsv = sm_wsum[tid * 2] + sm_wsum[tid * 2 + 1];
        const float b0 = sm_bval[tid * 2], b1 = sm_bval[tid * 2 + 1];
        const int   i0 = sm_bidx[tid * 2], i1 = sm_bidx[tid * 2 + 1];
        float bv; int bi;
        if (b0 > b1 || (b0 == b1 && i0 < i1)) { bv = b0; bi = i0; }
        else                                   { bv = b1; bi = i1; }
        const size_t o = (size_t)split * TOK + t0 + tid;
        wsW[o] = wsv; wsBV[o] = bv; wsBI[o] = bi;
    }
    #pragma unroll
    for (int i = 0; i < 4; ++i)
        #pragma unroll
        for (int j = 0; j < 4; ++j)
            #pragma unroll
            for (int r = 0; r < 4; ++r) {
                const int trow = wrow * 64 + i * 16 + fg * 4 + r;
                const int dd   = wcol * 64 + j * 16 + fr;
                wsE[((size_t)split * TOK + t0 + trow) * DIM + dd] = Eacc[i][j][r];
            }
}

// ---------------------------------------------------------------------------
__global__ __launch_bounds__(128) void combine_kernel(
    const int* __restrict__ inp_word, const float* __restrict__ masks,
    const int* __restrict__ spt_mask, const int* __restrict__ tgt_ids,
    const float* __restrict__ word_emb, const float* __restrict__ pcpy,
    const float* __restrict__ g_nrm,
    const float* __restrict__ nW, const float* __restrict__ nBV,
    const int* __restrict__ nBI, const float* __restrict__ nE, int NVn,
    const float* __restrict__ sW, const float* __restrict__ sBV,
    const int* __restrict__ sBI, const float* __restrict__ sE, int NVs,
    float* __restrict__ out)
{
    const int t = (int)blockIdx.x;
    const int d = (int)threadIdx.x;

    float Wn = 0.f, En = 0.f, bv = -INFINITY; int bi = 0;
    for (int v = 0; v < NVn; ++v) {
        const size_t o = (size_t)v * TOK + t;
        Wn += nW[o];
        En += nE[o * DIM + d];
        const float vv = nBV[o]; const int ii = nBI[o];
        if (vv > bv || (vv == bv && ii < bi)) { bv = vv; bi = ii; }
    }
    const int iw = inp_word[t];
    const float sc = pcpy[t] + g_nrm[(size_t)t * (NWRDC + 1) + NWRDC];
    const float ec = __expf(sc);
    Wn += ec;
    En += ec * word_emb[(size_t)iw * DIM + d];
    const int ynrm = (sc > bv) ? iw : bi;

    float Ws = 0.f, Ese = 0.f, sv = -INFINITY; int si = 0;
    for (int v = 0; v < NVs; ++v) {
        const size_t o = (size_t)v * TOK + t;
        Ws += sW[o];
        Ese += sE[o * DIM + d];
        const float vv = sBV[o]; const int ii = sBI[o];
        if (vv > sv || (vv == sv && ii < si)) { sv = vv; si = ii; }
    }
    const int yspt = tgt_ids[si];

    const float sptf = (float)spt_mask[t];
    const float nrmf = (1.f - sptf) * masks[t];

    float eo; int obf;
    if (sptf > 0.f)      { eo = Ese / Ws; obf = yspt; }
    else if (nrmf > 0.f) { eo = En / Wn;  obf = ynrm; }
    else                 { obf = iw; eo = word_emb[(size_t)iw * DIM + d]; }

    out[(size_t)t * DIM + d] = eo;
    if (d == 0) {
        out[(size_t)TOK * DIM + t]       = (float)obf;
        out[(size_t)TOK * DIM + TOK + t] = sptf;
    }
}

// ---------------------------------------------------------------------------
extern "C" void kernel_launch(void* const* d_in, const int* in_sizes, int n_in,
                              void* d_out, int out_size, void* d_ws, size_t ws_size,
                              hipStream_t stream)
{
    const int*   inp_word = (const int*)d_in[0];
    const float* masks    = (const float*)d_in[1];
    const int*   spt_mask = (const int*)d_in[2];
    const int*   tgt_ids  = (const int*)d_in[3];
    const float* ctx      = (const float*)d_in[4];
    const float* W_spt    = (const float*)d_in[5];
    const float* b_spt    = (const float*)d_in[6];
    const float* W_nrm    = (const float*)d_in[7];
    const float* b_nrm    = (const float*)d_in[8];
    const float* W_cpy    = (const float*)d_in[9];
    const float* b_cpy    = (const float*)d_in[10];
    const float* word_emb = (const float*)d_in[11];
    const float* word_emb_tgt = (const float*)d_in[12];
    const float* g_spt    = (const float*)d_in[13];
    const float* g_nrm    = (const float*)d_in[14];
    float* out = (float*)d_out;

    // ---- workspace carve (bytes) ----
    char* wsb = (char*)d_ws;
    float*  pcpy = (float*)wsb;                              // 4 KB
    ushort* ctxh = (ushort*)(wsb + 4096);                    // 2 MB
    ushort* ctxm = (ushort*)(wsb + 4096 + 2097152);          // 2 MB
    ushort* ctxl = (ushort*)(wsb + 4096 + 4194304);          // 2 MB
    char*   region = wsb + 4096 + 6291456;                   // 6295552
    float*  Cws = (float*)region;                            // 4 MB, dead after pcpy_dot

    const size_t per_split = (size_t)TOK * (DIM + 3) * 4;    // 536576 B
    size_t avail = (ws_size > 6295552) ? (ws_size - 6295552) / per_split : 0;
    int NVn, NVs;
    if      (avail >= 72) { NVn = 64; NVs = 8; }
    else if (avail >= 56) { NVn = 48; NVs = 8; }
    else if (avail >= 40) { NVn = 32; NVs = 8; }
    else if (avail >= 24) { NVn = 16; NVs = 8; }
    else if (avail >= 12) { NVn = 8;  NVs = 4; }
    else if (avail >= 3)  { NVn = (int)avail - 1; NVs = 1; }
    else                  { NVn = 1;  NVs = 1; }

    float* nW  = (float*)region;
    float* nBV = nW + (size_t)NVn * TOK;
    int*   nBI = (int*)(nBV + (size_t)NVn * TOK);
    float* nE  = (float*)(nBI + (size_t)NVn * TOK);
    float* sW  = nE + (size_t)NVn * TOK * DIM;
    float* sBV = sW + (size_t)NVs * TOK;
    int*   sBI = (int*)(sBV + (size_t)NVs * TOK);
    float* sE  = (float*)(sBI + (size_t)NVs * TOK);

    const int ntile_n = NWRDC / 128;                         // 250
    const int tps_n = (ntile_n + NVn - 1) / NVn;
    const int ntile_s = (NTGTC + 127) / 128;                 // 16
    const int tps_s = (ntile_s + NVs - 1) / NVs;

    split_ctx3<<<dim3(TOK * HSZ / 1024), dim3(256), 0, stream>>>(ctx, ctxh, ctxm, ctxl);
    gemm_cpy<<<dim3(8, 8), dim3(256), 0, stream>>>(ctxh, ctxm, ctxl, W_cpy, Cws);
    pcpy_dot<<<dim3(TOK), dim3(256), 0, stream>>>(Cws, ctx, b_cpy, pcpy);
    head_mfma<<<dim3(NVn, 8), dim3(256), 0, stream>>>(
        ctxh, ctxm, W_nrm, b_nrm, g_nrm, word_emb, NWRDC, NWRDC + 1,
        tps_n, ntile_n, nW, nBV, nBI, nE);
    head_mfma<<<dim3(NVs, 8), dim3(256), 0, stream>>>(
        ctxh, ctxm, W_spt, b_spt, g_spt, word_emb_tgt, NTGTC, NTGTC,
        tps_s, ntile_s, sW, sBV, sBI, sE);
    combine_kernel<<<dim3(TOK), dim3(128), 0, stream>>>(
        inp_word, masks, spt_mask, tgt_ids, word_emb, pcpy, g_nrm,
        nW, nBV, nBI, nE, NVn, sW, sBV, sBI, sE, NVs, out);
    (void)in_sizes; (void)n_in; (void)out_size;
}